// Round 1
// baseline (210.110 us; speedup 1.0000x reference)
//
#include <hip/hip_runtime.h>

// Problem constants
#define N_B   4
#define N_T   16
#define N_Y   256
#define N_X   256
#define PIX   65536        // N_Y*N_X
#define BATCHF 7340032     // floats per batch input = 112*65536

// Output float offsets
#define M_BASE     4194304
#define H_BASE     12582912
#define TAU_BASE   29360128

typedef float f4 __attribute__((ext_vector_type(4)));

__device__ __forceinline__ float sp10(float x) {
    // softplus(10x)/10 via HW transcendentals (v_exp_f32 / v_log_f32)
    float z = 10.0f * x;
    float e = __expf(-fabsf(z));
    float r = fmaxf(z, 0.0f) + __logf(1.0f + e);
    return r * 0.1f;
}

__device__ __forceinline__ f4 ntload(const float* p) {
    return __builtin_nontemporal_load(reinterpret_cast<const f4*>(p));
}
__device__ __forceinline__ void ntstore(float* p, f4 v) {
    __builtin_nontemporal_store(v, reinterpret_cast<f4*>(p));
}

__device__ __forceinline__ f4 sp4(f4 v) {
    f4 r;
    r.x = sp10(v.x); r.y = sp10(v.y); r.z = sp10(v.z); r.w = sp10(v.w);
    return r;
}

__global__ __launch_bounds__(256, 8)
void decode_param_kernel(const float* __restrict__ p, float* __restrict__ out) {
    // 64-x tile: rows of 64 + 4 pad (row stride 68 floats).
    // LDS = 3*16*68*4 = 12.75 KiB -> 8 blocks/CU (thread-capped), 32 waves/CU.
    // Phase-1 float4 writes; phase-2 column b32 reads are 2-way conflicts (free).
    __shared__ float l00[N_T][68];
    __shared__ float l01[N_T][68];
    __shared__ float l11[N_T][68];

    const int bid = blockIdx.x;
    const int tid = threadIdx.x;

    if (bid < 4096) {
        // ---- H blocks: one (b, y, 64-wide x tile) each ----
        const int xt = bid & 3;          // x tile 0..3
        const int y  = (bid >> 2) & 255; // row
        const int b  = bid >> 10;        // batch
        const int t  = tid >> 4;         // 0..15
        const int xq = tid & 15;         // quad index: x = xq*4 .. xq*4+3

        const long inbase = (long)b * BATCHF + (long)y * N_X + xt * 64 + xq * 4;
        const float* pg  = p + inbase + (long)(48 + t) * PIX;
        const float* pvx = p + inbase + (long)(64 + t) * PIX;
        const float* pvy = p + inbase + (long)(80 + t) * PIX;

        f4 g  = ntload(pg);
        f4 vx = ntload(pvx);
        f4 vy = ntload(pvy);

        g = sp4(g);

        *reinterpret_cast<f4*>(&l00[t][xq * 4]) = g + vx * vx;
        *reinterpret_cast<f4*>(&l01[t][xq * 4]) = vx * vy;
        *reinterpret_cast<f4*>(&l11[t][xq * 4]) = g + vy * vy;
        __syncthreads();

        // phase 2: thread handles one x value (xl) and one t-quad (tq)
        const int xl = tid >> 2;          // 0..63
        const int tq = (tid & 3) * 4;     // 0,4,8,12

        f4 a00, a01, a11;
        a00.x = l00[tq+0][xl]; a00.y = l00[tq+1][xl];
        a00.z = l00[tq+2][xl]; a00.w = l00[tq+3][xl];
        a01.x = l01[tq+0][xl]; a01.y = l01[tq+1][xl];
        a01.z = l01[tq+2][xl]; a01.w = l01[tq+3][xl];
        a11.x = l11[tq+0][xl]; a11.y = l11[tq+1][xl];
        a11.z = l11[tq+2][xl]; a11.w = l11[tq+3][xl];

        // out index: H_BASE + ((b*4 + comp)*65536 + y*256 + x)*16 + t
        const long outoff = (long)H_BASE + (long)b * 4194304 + (long)y * 4096
                          + xt * 1024 + xl * 16 + tq;
        ntstore(out + outoff,           a00);   // H00
        ntstore(out + outoff + 1048576, a01);   // H01
        ntstore(out + outoff + 2097152, a01);   // H10 == H01
        ntstore(out + outoff + 3145728, a11);   // H11
    } else {
        // ---- elementwise blocks: kappa / m-copy / tau, 2 float4 per thread ----
        const long j   = (long)(bid - 4096) * 256 + tid;  // 0 .. 2097151
        const int job  = (int)(j >> 17);
        const long r   = j & 131071;
        const int b    = job >> 2;
        const int kind = job & 3;

        const long inb = (long)b * (BATCHF / 4);
        long in4, out4;
        bool do_sp;
        if (kind == 0)      { in4 = inb;           out4 = (long)b * 262144;                 do_sp = true;  } // kappa
        else if (kind == 1) { in4 = inb + 262144;  out4 = M_BASE / 4 + (long)b * 524288;    do_sp = false; } // m c=0
        else if (kind == 2) { in4 = inb + 524288;  out4 = M_BASE / 4 + 262144 + (long)b * 524288; do_sp = false; } // m c=1
        else                { in4 = inb + 1572864; out4 = TAU_BASE / 4 + (long)b * 262144;  do_sp = true;  } // tau

        f4 v0 = ntload(p + (in4 + r) * 4);
        f4 v1 = ntload(p + (in4 + r + 131072) * 4);
        if (do_sp) { v0 = sp4(v0); v1 = sp4(v1); }
        ntstore(out + (out4 + r) * 4, v0);
        ntstore(out + (out4 + r + 131072) * 4, v1);
    }
}

extern "C" void kernel_launch(void* const* d_in, const int* in_sizes, int n_in,
                              void* d_out, int out_size, void* d_ws, size_t ws_size,
                              hipStream_t stream) {
    const float* p = (const float*)d_in[0];
    float* out = (float*)d_out;
    // 4096 H blocks + 8192 elementwise blocks
    decode_param_kernel<<<12288, 256, 0, stream>>>(p, out);
}